// Round 3
// baseline (214.126 us; speedup 1.0000x reference)
//
#include <hip/hip_runtime.h>
#include <math.h>

#define DM   1024
#define DS   64
#define BATCH 8
#define SEQ  2048
#define CL   32          // chunk length
#define NC   64          // number of chunks (SEQ/CL)

typedef __bf16 bf16x8 __attribute__((ext_vector_type(8)));
typedef float  f32x4  __attribute__((ext_vector_type(4)));

#if __has_builtin(__builtin_amdgcn_exp2f)
#define EXP2(v) __builtin_amdgcn_exp2f(v)
#else
#define EXP2(v) __expf(0.69314718056f * (v))
#endif

// ---------------------------------------------------------------------------
// Kernel W: pre-convert W_delta|W_Bp|W_Cp into packed bf16, K-tiled:
// Wp[(kt*192 + n)*32 + kk], k = kt*32+kk.  A 64-K block kb = contiguous
// 24 KB at Wp + kb*12288 elements.  (proven)
// ---------------------------------------------------------------------------
__global__ __launch_bounds__(256) void wconv_kernel(
    const float* __restrict__ Wd, const float* __restrict__ Wb,
    const float* __restrict__ Wc, __bf16* __restrict__ Wp)
{
    int idx = blockIdx.x * 256 + threadIdx.x;   // n*1024 + k
    int k  = idx & 1023;
    int n  = idx >> 10;                          // 0..191
    const float* W = (n < 64) ? Wd : (n < 128 ? Wb : Wc);
    float v = W[(size_t)(n & 63) * DM + k];
    int kt = k >> 5, kk = k & 31;
    Wp[((size_t)kt * 192 + n) * 32 + kk] = (__bf16)v;
}

// ---------------------------------------------------------------------------
// Kernel A+B fused: projection + pass1 local scan.
// GEMM is now 100% register-resident: A fragments load straight from x
// (float4 pairs -> bf16 cvt in regs), B fragments straight from L2-resident
// Wp (contiguous 1KB/row-slice per instr, coalesced).  NO LDS, NO barriers,
// NO vmcnt(0) drains in the K-loop.  2-stage pipeline: A f32 loads issued 2
// iters ahead, cvt 1 iter ahead; B reloaded right after use (~2-iter
// distance to next consumption).
// LDS: s_d + s_u = 16 KB only (epilogue->scan handoff).
// MFMA layouts (m89/m91): A/B frag [k=quad*8+j][m|n=l15]; D: col=l15,
// row=quad*4+reg.
// ---------------------------------------------------------------------------
__global__ __launch_bounds__(256, 2) void projp1_full(
    const float* __restrict__ x, const __bf16* __restrict__ Wp,
    const float* __restrict__ bd, const float* __restrict__ bb,
    const float* __restrict__ bc, const float* __restrict__ A_log,
    float* __restrict__ delta_g, float* __restrict__ u_g,
    float* __restrict__ ct_g,
    float* __restrict__ E, float* __restrict__ Dsum)
{
    __shared__ float  s_d[CL * 64];              // 8 KB
    __shared__ float  s_u[CL * 64];              // 8 KB

    const int tid  = threadIdx.x;
    const int row0 = blockIdx.x * 32;

    const int lane = tid & 63, wv = tid >> 6;
    const int l15  = lane & 15, quad = lane >> 4;
    const int nbase = wv * 48;                   // wave's N window

    // per-lane A row base: row l15 (and +16), k-window quad*8
    const float* xrow = x + (size_t)(row0 + l15) * DM + quad * 8;

    f32x4 acc[2][3];
    #pragma unroll
    for (int mt = 0; mt < 2; ++mt)
        #pragma unroll
        for (int nt = 0; nt < 3; ++nt)
            acc[mt][nt] = (f32x4){0.f, 0.f, 0.f, 0.f};

    float4 xf[2][8];      // f32 A pipeline, 2 deep
    bf16x8 af[2][4];      // cvt'd A frags [p][mt*2+s]
    bf16x8 bfr[2][6];     // B frags       [p][s*3+nt]

    #define LOADX(dst, kb) do {                                               \
        _Pragma("unroll")                                                     \
        for (int mt = 0; mt < 2; ++mt)                                        \
            _Pragma("unroll")                                                 \
            for (int s = 0; s < 2; ++s) {                                     \
                (dst)[mt*4 + s*2 + 0] = *(const float4*)(                     \
                    xrow + (size_t)mt * 16 * DM + (kb) * 64 + s * 32);        \
                (dst)[mt*4 + s*2 + 1] = *(const float4*)(                     \
                    xrow + (size_t)mt * 16 * DM + (kb) * 64 + s * 32 + 4);    \
            }                                                                 \
    } while (0)
    #define CVT(dst, src) do {                                               \
        _Pragma("unroll")                                                     \
        for (int f = 0; f < 4; ++f) {                                         \
            float4 lo = (src)[f*2], hi = (src)[f*2 + 1];                      \
            (dst)[f] = (bf16x8){(__bf16)lo.x, (__bf16)lo.y,                   \
                                (__bf16)lo.z, (__bf16)lo.w,                   \
                                (__bf16)hi.x, (__bf16)hi.y,                   \
                                (__bf16)hi.z, (__bf16)hi.w};                  \
        }                                                                     \
    } while (0)
    #define LOADBF(dst, kb) do {                                              \
        _Pragma("unroll")                                                     \
        for (int s = 0; s < 2; ++s)                                           \
            _Pragma("unroll")                                                 \
            for (int nt = 0; nt < 3; ++nt)                                    \
                (dst)[s*3 + nt] = *(const bf16x8*)(                           \
                    Wp + (size_t)(kb) * 12288 + s * 6144                      \
                       + (nbase + nt * 16 + l15) * 32 + quad * 8);            \
    } while (0)
    #define COMPUTE(afr, bfrr) do {                                          \
        _Pragma("unroll")                                                     \
        for (int s = 0; s < 2; ++s)                                           \
            _Pragma("unroll")                                                 \
            for (int nt = 0; nt < 3; ++nt) {                                  \
                _Pragma("unroll")                                             \
                for (int mt = 0; mt < 2; ++mt)                                \
                    acc[mt][nt] = __builtin_amdgcn_mfma_f32_16x16x32_bf16(    \
                        (afr)[mt*2 + s], (bfrr)[s*3 + nt], acc[mt][nt],       \
                        0, 0, 0);                                             \
            }                                                                 \
    } while (0)

    // prologue: kb0 + kb1 in flight, kb0 converted
    LOADX(xf[0], 0);  LOADBF(bfr[0], 0);
    LOADX(xf[1], 1);  LOADBF(bfr[1], 1);
    CVT(af[0], xf[0]);

    #pragma unroll
    for (int kb = 0; kb < 16; ++kb) {
        if (kb + 2 < 16) LOADX(xf[kb & 1], kb + 2);       // A f32, 2 ahead
        COMPUTE(af[kb & 1], bfr[kb & 1]);                  // 12 MFMA
        if (kb + 2 < 16) LOADBF(bfr[kb & 1], kb + 2);      // B, after use
        if (kb + 1 < 16) CVT(af[(kb & 1) ^ 1], xf[(kb & 1) ^ 1]); // cvt kb+1
    }
    #undef LOADX
    #undef CVT
    #undef LOADBF
    #undef COMPUTE

    // epilogue: bias + activations; store global AND stage delta/u in LDS
    #pragma unroll
    for (int nt = 0; nt < 3; ++nt) {
        int gn  = nbase + nt * 16 + l15;         // 0..191
        int mat = (nbase + nt * 16) >> 6;        // wave-uniform per nt
        int col = gn & 63;
        float bias = (mat == 0) ? bd[col] : (mat == 1 ? bb[col] : bc[col]);
        #pragma unroll
        for (int mt = 0; mt < 2; ++mt) {
            #pragma unroll
            for (int r = 0; r < 4; ++r) {
                int tl = mt * 16 + quad * 4 + r; // local t 0..31
                int m  = row0 + tl;
                float v = acc[mt][nt][r] + bias;
                if (mat == 0) {
                    float sp = (v > 20.f) ? v : __logf(1.f + __expf(v));
                    delta_g[(size_t)m * DS + col] = sp;
                    s_d[tl * 64 + col] = sp;
                } else if (mat == 1) {
                    float uu = v * x[(size_t)m * DM + col];
                    u_g[(size_t)m * DS + col] = uu;
                    s_u[tl * 64 + col] = uu;
                } else {
                    ct_g[(size_t)m * DS + col] = v;
                }
            }
        }
    }
    __syncthreads();

    // ---- fused pass1: local chunk scan from h=0 ----
    const int bidx = row0 >> 11;                 // batch  (row0/2048)
    const int cidx = (row0 >> 5) & 63;           // chunk  ((row0/32)%64)
    const int si = tid & 63;
    const int sj = tid >> 6;

    float alog[16];
    {
        const float4* ar = (const float4*)(A_log + si * 64 + sj * 16);
        #pragma unroll
        for (int qq = 0; qq < 4; ++qq) {
            float4 v = ar[qq];
            alog[4*qq+0] = v.x * 1.44269504f; alog[4*qq+1] = v.y * 1.44269504f;
            alog[4*qq+2] = v.z * 1.44269504f; alog[4*qq+3] = v.w * 1.44269504f;
        }
    }

    float h[16];
    #pragma unroll
    for (int k = 0; k < 16; ++k) h[k] = 0.f;
    float dsum = 0.f;

    for (int t = 0; t < CL; ++t) {
        float d = s_d[t * 64 + si];
        dsum += d;
        const float* up = s_u + t * 64 + sj * 16;
        #pragma unroll
        for (int k = 0; k < 16; ++k)
            h[k] = EXP2(alog[k] * d) * h[k] + up[k];
    }

    float* eo = E + (((size_t)cidx * BATCH + bidx) * 64 + si) * 64 + sj * 16;
    #pragma unroll
    for (int qq = 0; qq < 4; ++qq)
        ((float4*)eo)[qq] = make_float4(h[4*qq], h[4*qq+1], h[4*qq+2], h[4*qq+3]);
    if (sj == 0) Dsum[((size_t)cidx * BATCH + bidx) * 64 + si] = dsum;
}

// ---------------------------------------------------------------------------
// Pipelined affine-scan combine over records n0..n1-1 laid out as
// Db[(n*BATCH + b)*64 + i] / Eb[((n*BATCH + b)*64 + i)*64 + jg*16].
// 1-deep prefetch so the next record's L2/L3 latency hides under the
// current record's 16 exp2+fma chain.
// ---------------------------------------------------------------------------
__device__ __forceinline__ void scan_range(
    const float* __restrict__ Eb, const float* __restrict__ Db,
    int n0, int n1, int bb_, int i_, int jg_,
    const float* __restrict__ alog, float* __restrict__ h)
{
    if (n0 >= n1) return;
    size_t idx = ((size_t)n0 * BATCH + bb_) * 64 + i_;
    float dsA = Db[idx];
    const float4* ep = (const float4*)(Eb + idx * 64 + jg_ * 16);
    float4 e0 = ep[0], e1 = ep[1], e2 = ep[2], e3 = ep[3];
    for (int n = n0; n < n1; ++n) {
        float dsN = 0.f;
        float4 f0 = make_float4(0.f,0.f,0.f,0.f), f1 = f0, f2 = f0, f3 = f0;
        if (n + 1 < n1) {
            size_t idx2 = ((size_t)(n + 1) * BATCH + bb_) * 64 + i_;
            dsN = Db[idx2];
            const float4* fp = (const float4*)(Eb + idx2 * 64 + jg_ * 16);
            f0 = fp[0]; f1 = fp[1]; f2 = fp[2]; f3 = fp[3];
        }
        float ev[16] = {e0.x,e0.y,e0.z,e0.w, e1.x,e1.y,e1.z,e1.w,
                        e2.x,e2.y,e2.z,e2.w, e3.x,e3.y,e3.z,e3.w};
        #pragma unroll
        for (int k = 0; k < 16; ++k)
            h[k] = EXP2(alog[k] * dsA) * h[k] + ev[k];
        dsA = dsN; e0 = f0; e1 = f1; e2 = f2; e3 = f3;
    }
}

// ---------------------------------------------------------------------------
// Kernel G: group composites.  Block (g2,b2) folds chunks 8*g2..8*g2+7 into
// (Eg, Dg): decay exponents add (Dg = sum Dsum), Eg = 8-step scan from 0.
// ---------------------------------------------------------------------------
__global__ __launch_bounds__(256) void group_kernel(
    const float* __restrict__ E, const float* __restrict__ Dsum,
    const float* __restrict__ A_log,
    float* __restrict__ Eg, float* __restrict__ Dg)
{
    const int g2 = blockIdx.x >> 3, b2 = blockIdx.x & 7;
    const int tid = threadIdx.x;
    const int i  = tid >> 2;                          // 0..63
    const int jg = tid & 3;                           // 0..3

    float alog[16];
    {
        const float4* ar = (const float4*)(A_log + i * 64 + jg * 16);
        #pragma unroll
        for (int qq = 0; qq < 4; ++qq) {
            float4 v = ar[qq];
            alog[4*qq+0] = v.x * 1.44269504f; alog[4*qq+1] = v.y * 1.44269504f;
            alog[4*qq+2] = v.z * 1.44269504f; alog[4*qq+3] = v.w * 1.44269504f;
        }
    }

    float hg[16];
    #pragma unroll
    for (int k = 0; k < 16; ++k) hg[k] = 0.f;
    scan_range(E, Dsum, g2 * 8, g2 * 8 + 8, b2, i, jg, alog, hg);

    float4* ego = (float4*)(Eg + (((size_t)g2 * BATCH + b2) * 64 + i) * 64 + jg * 16);
    ego[0] = make_float4(hg[0],  hg[1],  hg[2],  hg[3]);
    ego[1] = make_float4(hg[4],  hg[5],  hg[6],  hg[7]);
    ego[2] = make_float4(hg[8],  hg[9],  hg[10], hg[11]);
    ego[3] = make_float4(hg[12], hg[13], hg[14], hg[15]);
    if (jg == 0) {
        float Dacc = 0.f;
        #pragma unroll
        for (int q = 0; q < 8; ++q)
            Dacc += Dsum[((size_t)(g2 * 8 + q) * BATCH + b2) * 64 + i];
        Dg[((size_t)g2 * BATCH + b2) * 64 + i] = Dacc;
    }
}

// ---------------------------------------------------------------------------
// Kernel C+D fused: each block (c,b) computes its OWN incoming state via the
// TWO-LEVEL prefix (<=7 group combines + <=7 chunk combines, prefetched),
// then replays the chunk and emits y.  (proven)
// ---------------------------------------------------------------------------
__global__ __launch_bounds__(256) void pass23_kernel(
    const float* __restrict__ delta_g, const float* __restrict__ u_g,
    const float* __restrict__ ct_g, const float* __restrict__ A_log,
    const float* __restrict__ E, const float* __restrict__ Dsum,
    const float* __restrict__ Eg, const float* __restrict__ Dg,
    float* __restrict__ out)
{
    __shared__ float s_d[CL * 64];
    __shared__ float s_u[CL * 64];
    __shared__ float s_c[CL * 64];

    const int c = blockIdx.x, b = blockIdx.y, tid = threadIdx.x;
    const int t0 = c * CL;

    const float4* dg = (const float4*)(delta_g + ((size_t)b * SEQ + t0) * DS);
    const float4* ug = (const float4*)(u_g     + ((size_t)b * SEQ + t0) * DS);
    const float4* cg = (const float4*)(ct_g    + ((size_t)b * SEQ + t0) * DS);
    #pragma unroll
    for (int it = 0; it < (CL * 64 / 4) / 256; ++it) {
        int f = tid + it * 256;
        ((float4*)s_d)[f] = dg[f];
        ((float4*)s_u)[f] = ug[f];
        ((float4*)s_c)[f] = cg[f];
    }

    const int i  = tid >> 2;                          // 0..63
    const int jg = tid & 3;                           // 0..3

    float alog[16];
    {
        const float4* ar = (const float4*)(A_log + i * 64 + jg * 16);
        #pragma unroll
        for (int qq = 0; qq < 4; ++qq) {
            float4 v = ar[qq];
            alog[4*qq+0] = v.x * 1.44269504f; alog[4*qq+1] = v.y * 1.44269504f;
            alog[4*qq+2] = v.z * 1.44269504f; alog[4*qq+3] = v.w * 1.44269504f;
        }
    }

    // ---- two-level prefix: groups 0..g-1, then chunks 8g..c-1 ----
    float h[16];
    #pragma unroll
    for (int k = 0; k < 16; ++k) h[k] = 0.f;
    const int g = c >> 3;
    scan_range(Eg, Dg, 0, g, b, i, jg, alog, h);
    scan_range(E, Dsum, g * 8, c, b, i, jg, alog, h);
    __syncthreads();

    // ---- replay + output ----
    for (int t = 0; t < CL; ++t) {
        float d = s_d[t * 64 + i];
        const float* up  = s_u + t * 64 + jg * 16;
        const float* cp2 = s_c + t * 64 + jg * 16;
        float part = 0.f;
        #pragma unroll
        for (int k = 0; k < 16; ++k) {
            h[k] = EXP2(alog[k] * d) * h[k] + up[k];
            part += cp2[k] * h[k];
        }
        part += __shfl_xor(part, 1);
        part += __shfl_xor(part, 2);
        if (jg == 0)
            out[((size_t)b * SEQ + t0 + t) * DS + i] = part;
    }
}

// ---------------------------------------------------------------------------
// Inputs: 0:x 1..6:(cog/beh/env dead) 7:W_delta 8:b_delta 9:W_Bp 10:b_Bp
//         11:W_Cp 12:b_Cp 13:A_log
// ---------------------------------------------------------------------------
extern "C" void kernel_launch(void* const* d_in, const int* in_sizes, int n_in,
                              void* d_out, int out_size, void* d_ws, size_t ws_size,
                              hipStream_t stream)
{
    (void)in_sizes; (void)n_in; (void)out_size; (void)ws_size;
    const float* x     = (const float*)d_in[0];
    const float* Wd    = (const float*)d_in[7];
    const float* bd    = (const float*)d_in[8];
    const float* Wb    = (const float*)d_in[9];
    const float* bb    = (const float*)d_in[10];
    const float* Wc    = (const float*)d_in[11];
    const float* bc    = (const float*)d_in[12];
    const float* A_log = (const float*)d_in[13];
    float* out = (float*)d_out;

    float* ws = (float*)d_ws;
    float* delta_g = ws;                       // 1,048,576 floats
    float* u_g     = ws + 1 * 1048576;         // 1,048,576
    float* ct_g    = ws + 2 * 1048576;         // 1,048,576
    float* E       = ws + 3 * 1048576;         // 2,097,152
    float* Dsum    = ws + 5242880;             // 32,768
    float* Eg      = ws + 5275648;             // 262,144
    float* Dg      = ws + 5537792;             // 4,096
    __bf16* Wp     = (__bf16*)(ws + 5541888);  // 196,608 bf16

    wconv_kernel<<<768, 256, 0, stream>>>(Wd, Wb, Wc, Wp);
    projp1_full<<<512, 256, 0, stream>>>(
        x, Wp, bd, bb, bc, A_log, delta_g, u_g, ct_g, E, Dsum);
    group_kernel<<<64, 256, 0, stream>>>(E, Dsum, A_log, Eg, Dg);
    pass23_kernel<<<dim3(NC, BATCH), 256, 0, stream>>>(
        delta_g, u_g, ct_g, A_log, E, Dsum, Eg, Dg, out);
}

// Round 4
// 170.282 us; speedup vs baseline: 1.2575x; 1.2575x over previous
//
#include <hip/hip_runtime.h>
#include <math.h>

#define DM   1024
#define DS   64
#define BATCH 8
#define SEQ  2048
#define CL   32          // chunk length
#define NC   64          // number of chunks (SEQ/CL)

typedef __bf16 bf16x8 __attribute__((ext_vector_type(8)));
typedef float  f32x4  __attribute__((ext_vector_type(4)));

#if __has_builtin(__builtin_amdgcn_exp2f)
#define EXP2(v) __builtin_amdgcn_exp2f(v)
#else
#define EXP2(v) __expf(0.69314718056f * (v))
#endif

// ---------------------------------------------------------------------------
// Kernel W: pre-convert W_delta|W_Bp|W_Cp into packed bf16, K-tiled:
// Wp[(kt*192 + n)*32 + kk], k = kt*32+kk.  A 64-K block kb = contiguous
// 24 KB at Wp + kb*12288 elements.  (proven)
// ---------------------------------------------------------------------------
__global__ __launch_bounds__(256) void wconv_kernel(
    const float* __restrict__ Wd, const float* __restrict__ Wb,
    const float* __restrict__ Wc, __bf16* __restrict__ Wp)
{
    int idx = blockIdx.x * 256 + threadIdx.x;   // n*1024 + k
    int k  = idx & 1023;
    int n  = idx >> 10;                          // 0..191
    const float* W = (n < 64) ? Wd : (n < 128 ? Wb : Wc);
    float v = W[(size_t)(n & 63) * DM + k];
    int kt = k >> 5, kk = k & 31;
    Wp[((size_t)kt * 192 + n) * 32 + kk] = (__bf16)v;
}

// ---------------------------------------------------------------------------
// Kernel A+B fused: projection + pass1 local scan.
// Structure = round-2 proven barrier-pinned loop, minus sB:
//  - B fragments read DIRECTLY from L2-resident Wp (each staged B byte was
//    consumed exactly once per block -> staging had zero reuse), prefetched
//    one K-block ahead into named regs.  Issue is pinned before the barrier
//    (__syncthreads is a memory fence), consumption right after -> the
//    barrier drain itself completes the prefetch under COMPUTE.
//  - sA widened to 4 buffers (one PAIR of 64-K blocks per stage) -> one
//    barrier per 2 K-blocks (8 drains instead of 16); x loaded a full pair
//    ahead so the load->stage distance is ~a whole iteration.
// All register arrays are literal-indexed (no dynamic reg indexing).
// LDS: 4*4.5 KB sA + 8 KB s_d + 8 KB s_u = 34 KB.
// MFMA layouts (m89/m91): A/B frag [k=quad*8+j][m|n=l15]; D: col=l15,
// row=quad*4+reg.
// ---------------------------------------------------------------------------
__global__ __launch_bounds__(256, 2) void projp1_full(
    const float* __restrict__ x, const __bf16* __restrict__ Wp,
    const float* __restrict__ bd, const float* __restrict__ bb,
    const float* __restrict__ bc, const float* __restrict__ A_log,
    float* __restrict__ delta_g, float* __restrict__ u_g,
    float* __restrict__ ct_g,
    float* __restrict__ E, float* __restrict__ Dsum)
{
    __shared__ __bf16 sA[4][32 * 72];            // 4 x 4.5 KB
    __shared__ float  s_d[CL * 64];              // 8 KB
    __shared__ float  s_u[CL * 64];              // 8 KB

    const int tid  = threadIdx.x;
    const int row0 = blockIdx.x * 32;

    const int lane = tid & 63, wv = tid >> 6;
    const int l15  = lane & 15, quad = lane >> 4;
    const int nbase = wv * 48;                   // wave's N window

    const int am = tid >> 3;                     // staging row 0..31
    const int ak = tid & 7;                      // 8-float k-group 0..7
    const float* xga = x + (size_t)(row0 + am) * DM + ak * 8;

    // per-lane B base inside a K-block: row (nbase+l15), k-offset quad*8
    const __bf16* wpb = Wp + (nbase + l15) * 32 + quad * 8;

    f32x4 acc[2][3];
    #pragma unroll
    for (int mt = 0; mt < 2; ++mt)
        #pragma unroll
        for (int nt = 0; nt < 3; ++nt)
            acc[mt][nt] = (f32x4){0.f, 0.f, 0.f, 0.f};

    float4 areg[4];                              // x for one K-block PAIR
    bf16x8 bA[6], bB[6];                         // B frags, named (no dyn idx)

    // x for pair pp (K-blocks 2pp, 2pp+1): 16 floats/thread
    #define LOADA2(pp) do {                                                   \
        areg[0] = *(const float4*)(xga + (pp) * 128);                         \
        areg[1] = *(const float4*)(xga + (pp) * 128 + 4);                     \
        areg[2] = *(const float4*)(xga + (pp) * 128 + 64);                    \
        areg[3] = *(const float4*)(xga + (pp) * 128 + 68);                    \
    } while (0)
    // stage areg (a pair) into sA[be] (even K-block) and sA[bo] (odd)
    #define STAGEA2(be, bo) do {                                              \
        bf16x8 h0 = {(__bf16)areg[0].x, (__bf16)areg[0].y,                    \
                     (__bf16)areg[0].z, (__bf16)areg[0].w,                    \
                     (__bf16)areg[1].x, (__bf16)areg[1].y,                    \
                     (__bf16)areg[1].z, (__bf16)areg[1].w};                   \
        *(bf16x8*)&sA[be][am * 72 + ak * 8] = h0;                             \
        bf16x8 h1 = {(__bf16)areg[2].x, (__bf16)areg[2].y,                    \
                     (__bf16)areg[2].z, (__bf16)areg[2].w,                    \
                     (__bf16)areg[3].x, (__bf16)areg[3].y,                    \
                     (__bf16)areg[3].z, (__bf16)areg[3].w};                   \
        *(bf16x8*)&sA[bo][am * 72 + ak * 8] = h1;                             \
    } while (0)
    // B frags for K-block kb, direct from global (1KB/instr coalesced)
    #define LOADBF(dst, kb) do {                                              \
        const __bf16* wb_ = wpb + (size_t)(kb) * 12288;                       \
        dst[0] = *(const bf16x8*)(wb_);                                       \
        dst[1] = *(const bf16x8*)(wb_ + 512);                                 \
        dst[2] = *(const bf16x8*)(wb_ + 1024);                                \
        dst[3] = *(const bf16x8*)(wb_ + 6144);                                \
        dst[4] = *(const bf16x8*)(wb_ + 6656);                                \
        dst[5] = *(const bf16x8*)(wb_ + 7168);                                \
    } while (0)
    #define COMPUTE(bi, bfr) do {                                             \
        _Pragma("unroll")                                                     \
        for (int s = 0; s < 2; ++s) {                                         \
            bf16x8 af0 = *(const bf16x8*)                                     \
                &sA[bi][(l15) * 72 + s * 32 + quad * 8];                      \
            bf16x8 af1 = *(const bf16x8*)                                     \
                &sA[bi][(16 + l15) * 72 + s * 32 + quad * 8];                 \
            _Pragma("unroll")                                                 \
            for (int nt = 0; nt < 3; ++nt) {                                  \
                acc[0][nt] = __builtin_amdgcn_mfma_f32_16x16x32_bf16(         \
                    af0, bfr[s * 3 + nt], acc[0][nt], 0, 0, 0);               \
                acc[1][nt] = __builtin_amdgcn_mfma_f32_16x16x32_bf16(         \
                    af1, bfr[s * 3 + nt], acc[1][nt], 0, 0, 0);               \
            }                                                                 \
        }                                                                     \
    } while (0)

    // prologue: pair0 staged (bufs 0,1), pair1 in regs, B frags for kb0
    LOADA2(0);
    STAGEA2(0, 1);
    LOADA2(1);
    LOADBF(bA, 0);
    __syncthreads();

    for (int p = 0; p < 8; ++p) {
        const int pe = (p & 1) * 2, po = pe + 1;     // LDS buf indices (addr math)
        LOADBF(bB, 2 * p + 1);                        // B odd, used this iter
        COMPUTE(pe, bA);                              // 12 MFMA, kb = 2p
        if (p < 7) STAGEA2(pe ^ 2, po ^ 2);           // stage pair p+1 (regs old)
        if (p < 6) LOADA2(p + 2);                     // x pair p+2, full iter ahead
        if (p < 7) LOADBF(bA, 2 * p + 2);             // B next even, crosses barrier
        COMPUTE(po, bB);                              // 12 MFMA, kb = 2p+1
        __syncthreads();                              // one drain per 2 K-blocks
    }
    #undef LOADA2
    #undef STAGEA2
    #undef LOADBF
    #undef COMPUTE

    // epilogue: bias + activations; store global AND stage delta/u in LDS
    #pragma unroll
    for (int nt = 0; nt < 3; ++nt) {
        int gn  = nbase + nt * 16 + l15;         // 0..191
        int mat = (nbase + nt * 16) >> 6;        // wave-uniform per nt
        int col = gn & 63;
        float bias = (mat == 0) ? bd[col] : (mat == 1 ? bb[col] : bc[col]);
        #pragma unroll
        for (int mt = 0; mt < 2; ++mt) {
            #pragma unroll
            for (int r = 0; r < 4; ++r) {
                int tl = mt * 16 + quad * 4 + r; // local t 0..31
                int m  = row0 + tl;
                float v = acc[mt][nt][r] + bias;
                if (mat == 0) {
                    float sp = (v > 20.f) ? v : __logf(1.f + __expf(v));
                    delta_g[(size_t)m * DS + col] = sp;
                    s_d[tl * 64 + col] = sp;
                } else if (mat == 1) {
                    float uu = v * x[(size_t)m * DM + col];
                    u_g[(size_t)m * DS + col] = uu;
                    s_u[tl * 64 + col] = uu;
                } else {
                    ct_g[(size_t)m * DS + col] = v;
                }
            }
        }
    }
    __syncthreads();

    // ---- fused pass1: local chunk scan from h=0 ----
    const int bidx = row0 >> 11;                 // batch  (row0/2048)
    const int cidx = (row0 >> 5) & 63;           // chunk  ((row0/32)%64)
    const int si = tid & 63;
    const int sj = tid >> 6;

    float alog[16];
    {
        const float4* ar = (const float4*)(A_log + si * 64 + sj * 16);
        #pragma unroll
        for (int qq = 0; qq < 4; ++qq) {
            float4 v = ar[qq];
            alog[4*qq+0] = v.x * 1.44269504f; alog[4*qq+1] = v.y * 1.44269504f;
            alog[4*qq+2] = v.z * 1.44269504f; alog[4*qq+3] = v.w * 1.44269504f;
        }
    }

    float h[16];
    #pragma unroll
    for (int k = 0; k < 16; ++k) h[k] = 0.f;
    float dsum = 0.f;

    for (int t = 0; t < CL; ++t) {
        float d = s_d[t * 64 + si];
        dsum += d;
        const float* up = s_u + t * 64 + sj * 16;
        #pragma unroll
        for (int k = 0; k < 16; ++k)
            h[k] = EXP2(alog[k] * d) * h[k] + up[k];
    }

    float* eo = E + (((size_t)cidx * BATCH + bidx) * 64 + si) * 64 + sj * 16;
    #pragma unroll
    for (int qq = 0; qq < 4; ++qq)
        ((float4*)eo)[qq] = make_float4(h[4*qq], h[4*qq+1], h[4*qq+2], h[4*qq+3]);
    if (sj == 0) Dsum[((size_t)cidx * BATCH + bidx) * 64 + si] = dsum;
}

// ---------------------------------------------------------------------------
// Pipelined affine-scan combine over records n0..n1-1 laid out as
// Db[(n*BATCH + b)*64 + i] / Eb[((n*BATCH + b)*64 + i)*64 + jg*16].
// 1-deep prefetch so the next record's L2/L3 latency hides under the
// current record's 16 exp2+fma chain.
// ---------------------------------------------------------------------------
__device__ __forceinline__ void scan_range(
    const float* __restrict__ Eb, const float* __restrict__ Db,
    int n0, int n1, int bb_, int i_, int jg_,
    const float* __restrict__ alog, float* __restrict__ h)
{
    if (n0 >= n1) return;
    size_t idx = ((size_t)n0 * BATCH + bb_) * 64 + i_;
    float dsA = Db[idx];
    const float4* ep = (const float4*)(Eb + idx * 64 + jg_ * 16);
    float4 e0 = ep[0], e1 = ep[1], e2 = ep[2], e3 = ep[3];
    for (int n = n0; n < n1; ++n) {
        float dsN = 0.f;
        float4 f0 = make_float4(0.f,0.f,0.f,0.f), f1 = f0, f2 = f0, f3 = f0;
        if (n + 1 < n1) {
            size_t idx2 = ((size_t)(n + 1) * BATCH + bb_) * 64 + i_;
            dsN = Db[idx2];
            const float4* fp = (const float4*)(Eb + idx2 * 64 + jg_ * 16);
            f0 = fp[0]; f1 = fp[1]; f2 = fp[2]; f3 = fp[3];
        }
        float ev[16] = {e0.x,e0.y,e0.z,e0.w, e1.x,e1.y,e1.z,e1.w,
                        e2.x,e2.y,e2.z,e2.w, e3.x,e3.y,e3.z,e3.w};
        #pragma unroll
        for (int k = 0; k < 16; ++k)
            h[k] = EXP2(alog[k] * dsA) * h[k] + ev[k];
        dsA = dsN; e0 = f0; e1 = f1; e2 = f2; e3 = f3;
    }
}

// ---------------------------------------------------------------------------
// Kernel G: group composites.  Block (g2,b2) folds chunks 8*g2..8*g2+7 into
// (Eg, Dg): decay exponents add (Dg = sum Dsum), Eg = 8-step scan from 0.
// ---------------------------------------------------------------------------
__global__ __launch_bounds__(256) void group_kernel(
    const float* __restrict__ E, const float* __restrict__ Dsum,
    const float* __restrict__ A_log,
    float* __restrict__ Eg, float* __restrict__ Dg)
{
    const int g2 = blockIdx.x >> 3, b2 = blockIdx.x & 7;
    const int tid = threadIdx.x;
    const int i  = tid >> 2;                          // 0..63
    const int jg = tid & 3;                           // 0..3

    float alog[16];
    {
        const float4* ar = (const float4*)(A_log + i * 64 + jg * 16);
        #pragma unroll
        for (int qq = 0; qq < 4; ++qq) {
            float4 v = ar[qq];
            alog[4*qq+0] = v.x * 1.44269504f; alog[4*qq+1] = v.y * 1.44269504f;
            alog[4*qq+2] = v.z * 1.44269504f; alog[4*qq+3] = v.w * 1.44269504f;
        }
    }

    float hg[16];
    #pragma unroll
    for (int k = 0; k < 16; ++k) hg[k] = 0.f;
    scan_range(E, Dsum, g2 * 8, g2 * 8 + 8, b2, i, jg, alog, hg);

    float4* ego = (float4*)(Eg + (((size_t)g2 * BATCH + b2) * 64 + i) * 64 + jg * 16);
    ego[0] = make_float4(hg[0],  hg[1],  hg[2],  hg[3]);
    ego[1] = make_float4(hg[4],  hg[5],  hg[6],  hg[7]);
    ego[2] = make_float4(hg[8],  hg[9],  hg[10], hg[11]);
    ego[3] = make_float4(hg[12], hg[13], hg[14], hg[15]);
    if (jg == 0) {
        float Dacc = 0.f;
        #pragma unroll
        for (int q = 0; q < 8; ++q)
            Dacc += Dsum[((size_t)(g2 * 8 + q) * BATCH + b2) * 64 + i];
        Dg[((size_t)g2 * BATCH + b2) * 64 + i] = Dacc;
    }
}

// ---------------------------------------------------------------------------
// Kernel C+D fused: each block (c,b) computes its OWN incoming state via the
// TWO-LEVEL prefix (<=7 group combines + <=7 chunk combines, prefetched),
// then replays the chunk and emits y.  (proven)
// ---------------------------------------------------------------------------
__global__ __launch_bounds__(256) void pass23_kernel(
    const float* __restrict__ delta_g, const float* __restrict__ u_g,
    const float* __restrict__ ct_g, const float* __restrict__ A_log,
    const float* __restrict__ E, const float* __restrict__ Dsum,
    const float* __restrict__ Eg, const float* __restrict__ Dg,
    float* __restrict__ out)
{
    __shared__ float s_d[CL * 64];
    __shared__ float s_u[CL * 64];
    __shared__ float s_c[CL * 64];

    const int c = blockIdx.x, b = blockIdx.y, tid = threadIdx.x;
    const int t0 = c * CL;

    const float4* dg = (const float4*)(delta_g + ((size_t)b * SEQ + t0) * DS);
    const float4* ug = (const float4*)(u_g     + ((size_t)b * SEQ + t0) * DS);
    const float4* cg = (const float4*)(ct_g    + ((size_t)b * SEQ + t0) * DS);
    #pragma unroll
    for (int it = 0; it < (CL * 64 / 4) / 256; ++it) {
        int f = tid + it * 256;
        ((float4*)s_d)[f] = dg[f];
        ((float4*)s_u)[f] = ug[f];
        ((float4*)s_c)[f] = cg[f];
    }

    const int i  = tid >> 2;                          // 0..63
    const int jg = tid & 3;                           // 0..3

    float alog[16];
    {
        const float4* ar = (const float4*)(A_log + i * 64 + jg * 16);
        #pragma unroll
        for (int qq = 0; qq < 4; ++qq) {
            float4 v = ar[qq];
            alog[4*qq+0] = v.x * 1.44269504f; alog[4*qq+1] = v.y * 1.44269504f;
            alog[4*qq+2] = v.z * 1.44269504f; alog[4*qq+3] = v.w * 1.44269504f;
        }
    }

    // ---- two-level prefix: groups 0..g-1, then chunks 8g..c-1 ----
    float h[16];
    #pragma unroll
    for (int k = 0; k < 16; ++k) h[k] = 0.f;
    const int g = c >> 3;
    scan_range(Eg, Dg, 0, g, b, i, jg, alog, h);
    scan_range(E, Dsum, g * 8, c, b, i, jg, alog, h);
    __syncthreads();

    // ---- replay + output ----
    for (int t = 0; t < CL; ++t) {
        float d = s_d[t * 64 + i];
        const float* up  = s_u + t * 64 + jg * 16;
        const float* cp2 = s_c + t * 64 + jg * 16;
        float part = 0.f;
        #pragma unroll
        for (int k = 0; k < 16; ++k) {
            h[k] = EXP2(alog[k] * d) * h[k] + up[k];
            part += cp2[k] * h[k];
        }
        part += __shfl_xor(part, 1);
        part += __shfl_xor(part, 2);
        if (jg == 0)
            out[((size_t)b * SEQ + t0 + t) * DS + i] = part;
    }
}

// ---------------------------------------------------------------------------
// Inputs: 0:x 1..6:(cog/beh/env dead) 7:W_delta 8:b_delta 9:W_Bp 10:b_Bp
//         11:W_Cp 12:b_Cp 13:A_log
// ---------------------------------------------------------------------------
extern "C" void kernel_launch(void* const* d_in, const int* in_sizes, int n_in,
                              void* d_out, int out_size, void* d_ws, size_t ws_size,
                              hipStream_t stream)
{
    (void)in_sizes; (void)n_in; (void)out_size; (void)ws_size;
    const float* x     = (const float*)d_in[0];
    const float* Wd    = (const float*)d_in[7];
    const float* bd    = (const float*)d_in[8];
    const float* Wb    = (const float*)d_in[9];
    const float* bb    = (const float*)d_in[10];
    const float* Wc    = (const float*)d_in[11];
    const float* bc    = (const float*)d_in[12];
    const float* A_log = (const float*)d_in[13];
    float* out = (float*)d_out;

    float* ws = (float*)d_ws;
    float* delta_g = ws;                       // 1,048,576 floats
    float* u_g     = ws + 1 * 1048576;         // 1,048,576
    float* ct_g    = ws + 2 * 1048576;         // 1,048,576
    float* E       = ws + 3 * 1048576;         // 2,097,152
    float* Dsum    = ws + 5242880;             // 32,768
    float* Eg      = ws + 5275648;             // 262,144
    float* Dg      = ws + 5537792;             // 4,096
    __bf16* Wp     = (__bf16*)(ws + 5541888);  // 196,608 bf16

    wconv_kernel<<<768, 256, 0, stream>>>(Wd, Wb, Wc, Wp);
    projp1_full<<<512, 256, 0, stream>>>(
        x, Wp, bd, bb, bc, A_log, delta_g, u_g, ct_g, E, Dsum);
    group_kernel<<<64, 256, 0, stream>>>(E, Dsum, A_log, Eg, Dg);
    pass23_kernel<<<dim3(NC, BATCH), 256, 0, stream>>>(
        delta_g, u_g, ct_g, A_log, E, Dsum, Eg, Dg, out);
}